// Round 7
// baseline (838.921 us; speedup 1.0000x reference)
//
#include <hip/hip_runtime.h>
#include <hip/hip_bf16.h>

typedef __hip_bfloat16 bf16;

static constexpr int HN  = 4;     // heads
static constexpr int NB  = 8;     // batch
static constexpr int SEQ = 1024;  // nodes
static constexpr int EMB = 128;
static constexpr int KD  = 32;
static constexpr int FFH = 512;
static constexpr int ROWS = NB * SEQ;       // 8192
static constexpr float EPS = 1e-5f;

__device__ __forceinline__ float b2f(bf16 x){ return __bfloat162float(x); }

// dtype-dispatched load: flag==1 -> buffer is float32, else bf16
__device__ __forceinline__ float ldx(const void* p, size_t i, int f32){
    return f32 ? ((const float*)p)[i] : b2f(((const bf16*)p)[i]);
}

// ---------------- K0: per-input dtype detector ----------------------------
__device__ __forceinline__ float probe_max(const unsigned int* w, int nwords, int t){
    float mx = 0.f;
    for (int i = t; i < nwords; i += 256) {
        float v = fabsf(__uint_as_float(w[i] << 16));
        if (!(v <= 1e4f)) v = 1e30f;
        mx = fmaxf(mx, v);
    }
    return mx;
}

// flags: 0=input1 1=input2 2=Wq 3=Wk 4=Wv 5=Wo 6=tinyMLP 7=Wff1 8=Wff2
__global__ __launch_bounds__(256) void detect_kernel(
    const unsigned int* in1, const unsigned int* in2,
    const unsigned int* wq,  const unsigned int* wk, const unsigned int* wv,
    const unsigned int* wo,  const unsigned int* ws1, const unsigned int* bs1,
    const unsigned int* ws2, const unsigned int* bs2,
    const unsigned int* wf1, const unsigned int* wf2, int* __restrict__ flags)
{
    __shared__ float red[4];
    const int b = blockIdx.x, t = threadIdx.x;
    float mx = 0.f;
    if      (b == 0) mx = probe_max(in1, 4096, t);
    else if (b == 1) mx = probe_max(in2, 4096, t);
    else if (b == 2) mx = probe_max(wq, 4096, t);
    else if (b == 3) mx = probe_max(wk, 4096, t);
    else if (b == 4) mx = probe_max(wv, 4096, t);
    else if (b == 5) mx = probe_max(wo, 4096, t);
    else if (b == 6) {
        mx = fmaxf(probe_max(ws1, 32, t), probe_max(bs1, 4, t));
        mx = fmaxf(mx, fmaxf(probe_max(ws2, 16, t), probe_max(bs2, 2, t)));
    }
    else if (b == 7) mx = probe_max(wf1, 4096, t);
    else             mx = probe_max(wf2, 4096, t);

    #pragma unroll
    for (int off = 32; off >= 1; off >>= 1) mx = fmaxf(mx, __shfl_xor(mx, off));
    if ((t & 63) == 0) red[t >> 6] = mx;
    __syncthreads();
    if (t == 0) {
        mx = fmaxf(fmaxf(red[0], red[1]), fmaxf(red[2], red[3]));
        flags[b] = (mx > 1e4f) ? 1 : 0;
    }
}

// ---------------- K0b: resolve dtypes + transpose weights ONCE ------------
__global__ __launch_bounds__(256) void convert_kernel(
    const void* in1, const void* Wq, const void* Wk, const void* Wv, const void* Wo,
    const void* Ws1, const void* bs1, const void* Ws2, const void* bs2,
    const void* Wf1, const void* Wf2,
    float* __restrict__ h32, float* __restrict__ Wt, float* __restrict__ Wot,
    float* __restrict__ W1t, float* __restrict__ W2t, float* __restrict__ mlp32,
    const int* __restrict__ flags)
{
    int gid = blockIdx.x * 256 + threadIdx.x;
    if (gid < 262144) {                         // input1 -> f32, 4 elems/thread
        if (flags[0]) {
            ((float4*)h32)[gid] = ((const float4*)in1)[gid];
        } else {
            const bf16* p = (const bf16*)in1 + (size_t)gid * 4;
            h32[gid*4+0] = b2f(p[0]); h32[gid*4+1] = b2f(p[1]);
            h32[gid*4+2] = b2f(p[2]); h32[gid*4+3] = b2f(p[3]);
        }
        return;
    }
    int r = gid - 262144;
    if (r < 49152) {                            // Wt[mat][h][k][e] = W[h][e][k]
        int mat = r >> 14, q = r & 16383;
        int h = q >> 12, k = (q >> 7) & 31, e = q & 127;
        const void* W = (mat == 0) ? Wq : (mat == 1) ? Wk : Wv;
        Wt[r] = ldx(W, (size_t)(h*EMB + e)*KD + k, flags[2+mat]);
        return;
    }
    r -= 49152;
    if (r < 16384) {                            // Wot[e][hk] = Wo[hk][e]
        int e = r >> 7, hk = r & 127;
        Wot[r] = ldx(Wo, (size_t)hk*EMB + e, flags[5]);
        return;
    }
    r -= 16384;
    if (r < 65536) {                            // W1t[f][e] = Wf1[e][f]
        int f = r >> 7, e = r & 127;
        W1t[r] = ldx(Wf1, (size_t)e*FFH + f, flags[7]);
        return;
    }
    r -= 65536;
    if (r < 65536) {                            // W2t[e][f] = Wf2[f][e]
        int e = r >> 9, f = r & 511;
        W2t[r] = ldx(Wf2, (size_t)f*EMB + e, flags[8]);
        return;
    }
    r -= 65536;
    if (r < 108) {
        const int fm = flags[6];
        float v;
        if (r < 64)       { int j = r >> 3, i = r & 7; v = ldx(Ws1, i*8 + j, fm); }
        else if (r < 72)  v = ldx(bs1, r - 64, fm);
        else if (r < 104) v = ldx(Ws2, r - 72, fm);    // w2[j][c] row-major kept
        else              v = ldx(bs2, r - 104, fm);
        mlp32[r] = v;
    }
}

// ---------------- K1: QKV projection, LDS-tiled GEMM ----------------------
// Outputs (all f32): Q32[h][row][k], Kt32[h][b][k][n], Vt32[h][b][k][n]
__global__ __launch_bounds__(256) void qkv_kernel(
    const float* __restrict__ h32, const float* __restrict__ Wt,
    float* __restrict__ Q32, float* __restrict__ Kt32, float* __restrict__ Vt32)
{
    __shared__ float hl[128 * 132];
    const int t   = threadIdx.x;
    const int bid = blockIdx.x;
    const int mat = bid >> 8;                   // 768 = 3 * 4 * 64
    const int hh  = (bid >> 6) & 3;
    const int rt  = bid & 63;
    const int row0 = rt * 128;

    #pragma unroll
    for (int i = 0; i < 16; i++) {
        int idx = t + 256 * i;
        int r  = idx >> 5;
        int e4 = (idx & 31) * 4;
        float4 v = *reinterpret_cast<const float4*>(h32 + (size_t)(row0 + r) * EMB + e4);
        *reinterpret_cast<float4*>(&hl[r * 132 + e4]) = v;
    }
    __syncthreads();

    const int rq = t >> 3;
    const int kq = t & 7;
    const float* wbase = Wt + ((size_t)(mat * HN + hh) * KD + kq * 4) * EMB;
    float acc[4][4] = {};
    #pragma unroll 4
    for (int eq = 0; eq < 32; eq++) {
        float4 a0 = *reinterpret_cast<const float4*>(&hl[(rq*4+0)*132 + eq*4]);
        float4 a1 = *reinterpret_cast<const float4*>(&hl[(rq*4+1)*132 + eq*4]);
        float4 a2 = *reinterpret_cast<const float4*>(&hl[(rq*4+2)*132 + eq*4]);
        float4 a3 = *reinterpret_cast<const float4*>(&hl[(rq*4+3)*132 + eq*4]);
        float4 w0 = *reinterpret_cast<const float4*>(wbase + 0*EMB + eq*4);
        float4 w1 = *reinterpret_cast<const float4*>(wbase + 1*EMB + eq*4);
        float4 w2 = *reinterpret_cast<const float4*>(wbase + 2*EMB + eq*4);
        float4 w3 = *reinterpret_cast<const float4*>(wbase + 3*EMB + eq*4);
        #pragma unroll
        for (int kk = 0; kk < 4; kk++) {
            float4 w = (kk==0)?w0:(kk==1)?w1:(kk==2)?w2:w3;
            acc[0][kk] += a0.x*w.x + a0.y*w.y + a0.z*w.z + a0.w*w.w;
            acc[1][kk] += a1.x*w.x + a1.y*w.y + a1.z*w.z + a1.w*w.w;
            acc[2][kk] += a2.x*w.x + a2.y*w.y + a2.z*w.z + a2.w*w.w;
            acc[3][kk] += a3.x*w.x + a3.y*w.y + a3.z*w.z + a3.w*w.w;
        }
    }

    if (mat == 0) {
        #pragma unroll
        for (int r = 0; r < 4; r++) {
            float4 v = { acc[r][0], acc[r][1], acc[r][2], acc[r][3] };
            *reinterpret_cast<float4*>(Q32 + ((size_t)hh*ROWS + row0 + rq*4 + r)*KD + kq*4) = v;
        }
    } else {
        float* out = (mat == 1) ? Kt32 : Vt32;
        int bb = row0 >> 10;
        int n0 = (row0 & 1023) + rq * 4;
        #pragma unroll
        for (int kk = 0; kk < 4; kk++) {
            float4 v = { acc[0][kk], acc[1][kk], acc[2][kk], acc[3][kk] };
            *reinterpret_cast<float4*>(out + ((size_t)(hh*NB + bb)*KD + kq*4 + kk)*SEQ + n0) = v;
        }
    }
}

// Phase-2 tiny-MLP row body. Macro (not function) so sz/wm stay LDS-addressed;
// ALL private arrays are compile-time indexed (rule #20: nothing may spill).
#define MLP_ROW(R, V0, V1, V2, V3)                                            \
    {                                                                          \
        float x0[8], x1[8], x2[8], x3[8];                                      \
        _Pragma("unroll")                                                      \
        for (int h = 0; h < 4; h++) {                                          \
            float4 s4 = *reinterpret_cast<const float4*>(&sz[(h*2+(R))*SEQ + m0]); \
            x0[h]=s4.x; x1[h]=s4.y; x2[h]=s4.z; x3[h]=s4.w;                    \
        }                                                                      \
        x0[4]=(V0).x; x1[4]=(V0).y; x2[4]=(V0).z; x3[4]=(V0).w;                \
        x0[5]=(V1).x; x1[5]=(V1).y; x2[5]=(V1).z; x3[5]=(V1).w;                \
        x0[6]=(V2).x; x1[6]=(V2).y; x2[6]=(V2).z; x3[6]=(V2).w;                \
        x0[7]=(V3).x; x1[7]=(V3).y; x2[7]=(V3).z; x3[7]=(V3).w;                \
        float zc[4][4];                                                        \
        _Pragma("unroll")                                                      \
        for (int m = 0; m < 4; m++) {                                          \
            _Pragma("unroll")                                                  \
            for (int c = 0; c < 4; c++) zc[m][c] = wm[104 + c];                \
        }                                                                      \
        _Pragma("unroll")                                                      \
        for (int j = 0; j < 8; j++) {                                          \
            float4 wa = *reinterpret_cast<const float4*>(&wm[j*8]);            \
            float4 wb = *reinterpret_cast<const float4*>(&wm[j*8+4]);          \
            float b1j = wm[64 + j];                                            \
            float4 w2v = *reinterpret_cast<const float4*>(&wm[72 + j*4]);      \
            float y0 = b1j + x0[0]*wa.x + x0[1]*wa.y + x0[2]*wa.z + x0[3]*wa.w \
                           + x0[4]*wb.x + x0[5]*wb.y + x0[6]*wb.z + x0[7]*wb.w;\
            float y1 = b1j + x1[0]*wa.x + x1[1]*wa.y + x1[2]*wa.z + x1[3]*wa.w \
                           + x1[4]*wb.x + x1[5]*wb.y + x1[6]*wb.z + x1[7]*wb.w;\
            float y2 = b1j + x2[0]*wa.x + x2[1]*wa.y + x2[2]*wa.z + x2[3]*wa.w \
                           + x2[4]*wb.x + x2[5]*wb.y + x2[6]*wb.z + x2[7]*wb.w;\
            float y3 = b1j + x3[0]*wa.x + x3[1]*wa.y + x3[2]*wa.z + x3[3]*wa.w \
                           + x3[4]*wb.x + x3[5]*wb.y + x3[6]*wb.z + x3[7]*wb.w;\
            y0 = fmaxf(y0, 0.f); y1 = fmaxf(y1, 0.f);                          \
            y2 = fmaxf(y2, 0.f); y3 = fmaxf(y3, 0.f);                          \
            zc[0][0] += y0*w2v.x; zc[0][1] += y0*w2v.y; zc[0][2] += y0*w2v.z; zc[0][3] += y0*w2v.w; \
            zc[1][0] += y1*w2v.x; zc[1][1] += y1*w2v.y; zc[1][2] += y1*w2v.z; zc[1][3] += y1*w2v.w; \
            zc[2][0] += y2*w2v.x; zc[2][1] += y2*w2v.y; zc[2][2] += y2*w2v.z; zc[2][3] += y2*w2v.w; \
            zc[3][0] += y3*w2v.x; zc[3][1] += y3*w2v.y; zc[3][2] += y3*w2v.z; zc[3][3] += y3*w2v.w; \
        }                                                                      \
        _Pragma("unroll")                                                      \
        for (int c = 0; c < 4; c++)                                            \
            *reinterpret_cast<float4*>(&sz[(c*2 + (R))*SEQ + m0]) =            \
                make_float4(zc[0][c], zc[1][c], zc[2][c], zc[3][c]);           \
    }

// ---------------- K2: fused attention, 2 rows per block -------------------
// LDS plane map: scores s[h][r] -> plane h*2+r; logits z[c][r] -> plane c*2+r
// (row body R reads planes {h*2+R} at its private m-window then writes the
//  same plane set - in-thread ordering preserved, other-row planes untouched)
__global__ __launch_bounds__(256, 3) void attn_kernel(
    const float* __restrict__ Q32, const float* __restrict__ Kt32,
    const float* __restrict__ Vt32, const void* __restrict__ in2,
    const float* __restrict__ mlp, float* __restrict__ heads,
    const int* __restrict__ flags)
{
    __shared__ float sz[8704];          // 8 planes [1024] ∪ red[4][32][68]
    __shared__ float qld[HN][2][KD];
    __shared__ float wm[108];
    __shared__ float invs[2][HN];

    const int t = threadIdx.x;
    // XCD swizzle: contiguous 512-block chunk (one batch) per XCD.
    const int wg   = (blockIdx.x & 7) * 512 + (blockIdx.x >> 3);
    const int row0 = wg * 2;
    const int b    = row0 >> 10;
    const int n0   = row0 & (SEQ - 1);
    const int m0   = t * 4;
    const int f2   = flags[1];
    const int w    = t >> 6, l = t & 63;

    { int h = t >> 6, r = (t >> 5) & 1, k = t & 31;
      qld[h][r][k] = Q32[((size_t)h*ROWS + row0 + r)*KD + k]; }
    if (t < 108) wm[t] = mlp[t];

    // in2 prefetch into NAMED float4 scalars (no array -> cannot spill via
    // dynamic indexing). Issued early; consumed in Phase 2.
    auto ld2 = [&](int c, int r) -> float4 {
        size_t base = ((size_t)(c*NB + b)*SEQ + (n0 + r))*SEQ + m0;
        if (f2) return *reinterpret_cast<const float4*>((const float*)in2 + base);
        ushort4 u = *reinterpret_cast<const ushort4*>((const ushort*)in2 + base);
        return make_float4(
            __uint_as_float((unsigned)u.x << 16), __uint_as_float((unsigned)u.y << 16),
            __uint_as_float((unsigned)u.z << 16), __uint_as_float((unsigned)u.w << 16));
    };
    float4 iA0 = ld2(0,0), iA1 = ld2(1,0), iA2 = ld2(2,0), iA3 = ld2(3,0);
    float4 iB0 = ld2(0,1), iB1 = ld2(1,1), iB2 = ld2(2,1), iB3 = ld2(3,1);
    __syncthreads();

    // ---- Phase 1: wave w = head w; both rows; float4 K loads ----
    {
        float q0[KD], q1[KD];
        const float4* qp0 = reinterpret_cast<const float4*>(&qld[w][0][0]);
        const float4* qp1 = reinterpret_cast<const float4*>(&qld[w][1][0]);
        #pragma unroll
        for (int i = 0; i < 8; i++) {
            float4 a = qp0[i], c = qp1[i];
            q0[4*i+0]=a.x; q0[4*i+1]=a.y; q0[4*i+2]=a.z; q0[4*i+3]=a.w;
            q1[4*i+0]=c.x; q1[4*i+1]=c.y; q1[4*i+2]=c.z; q1[4*i+3]=c.w;
        }
        const float* kb = Kt32 + ((size_t)(w*NB + b)*KD)*SEQ;
        #pragma unroll 2
        for (int mc = 0; mc < 4; mc++) {
            const int m = mc*256 + l*4;
            float a0x=0.f,a0y=0.f,a0z=0.f,a0w=0.f;
            float a1x=0.f,a1y=0.f,a1z=0.f,a1w=0.f;
            #pragma unroll
            for (int k = 0; k < KD; k++) {
                float4 kv = *reinterpret_cast<const float4*>(kb + (size_t)k*SEQ + m);
                a0x += q0[k]*kv.x; a0y += q0[k]*kv.y; a0z += q0[k]*kv.z; a0w += q0[k]*kv.w;
                a1x += q1[k]*kv.x; a1y += q1[k]*kv.y; a1z += q1[k]*kv.z; a1w += q1[k]*kv.w;
            }
            *reinterpret_cast<float4*>(&sz[(w*2+0)*SEQ + m]) = make_float4(a0x,a0y,a0z,a0w);
            *reinterpret_cast<float4*>(&sz[(w*2+1)*SEQ + m]) = make_float4(a1x,a1y,a1z,a1w);
        }
    }
    __syncthreads();

    // ---- Phase 2: tiny MLP, two explicit row bodies (all-static indices) ----
    MLP_ROW(0, iA0, iA1, iA2, iA3)
    MLP_ROW(1, iB0, iB1, iB2, iB3)
    __syncthreads();

    // ---- Phase 3: wave w = head w softmax; lane l owns m in {4l+256i} ----
    // 16B lane stride -> conflict-free LDS reads.
    float p0[16], p1[16];
    {
        #pragma unroll
        for (int i = 0; i < 4; i++) {
            float4 a = *reinterpret_cast<const float4*>(&sz[(w*2+0)*SEQ + i*256 + l*4]);
            float4 c = *reinterpret_cast<const float4*>(&sz[(w*2+1)*SEQ + i*256 + l*4]);
            p0[4*i+0]=a.x; p0[4*i+1]=a.y; p0[4*i+2]=a.z; p0[4*i+3]=a.w;
            p1[4*i+0]=c.x; p1[4*i+1]=c.y; p1[4*i+2]=c.z; p1[4*i+3]=c.w;
        }
        float mx0 = -1e30f, mx1 = -1e30f;
        #pragma unroll
        for (int i = 0; i < 16; i++) { mx0 = fmaxf(mx0, p0[i]); mx1 = fmaxf(mx1, p1[i]); }
        #pragma unroll
        for (int off = 32; off >= 1; off >>= 1) {
            mx0 = fmaxf(mx0, __shfl_xor(mx0, off));
            mx1 = fmaxf(mx1, __shfl_xor(mx1, off));
        }
        float s0 = 0.f, s1 = 0.f;
        #pragma unroll
        for (int i = 0; i < 16; i++) {
            p0[i] = __expf(p0[i] - mx0); s0 += p0[i];
            p1[i] = __expf(p1[i] - mx1); s1 += p1[i];
        }
        #pragma unroll
        for (int off = 32; off >= 1; off >>= 1) { s0 += __shfl_xor(s0, off); s1 += __shfl_xor(s1, off); }
        if (l == 0) { invs[0][w] = 1.f / s0; invs[1][w] = 1.f / s1; }
    }
    __syncthreads();                     // z consumed -> sz reusable as red

    // ---- Phase 4: PV in two k-halves (16 accs/row, NOT 32) ----
    #pragma unroll 1
    for (int kh = 0; kh < 2; kh++) {
        float o0[16], o1[16];
        #pragma unroll
        for (int i = 0; i < 16; i++) { o0[i] = 0.f; o1[i] = 0.f; }
        const float* vb = Vt32 + ((size_t)(w*NB + b)*KD + kh*16)*SEQ + l*4;
        #pragma unroll
        for (int k16 = 0; k16 < 16; k16++) {
            const float* vk = vb + (size_t)k16*SEQ;
            float4 v0 = *reinterpret_cast<const float4*>(vk + 0*256);
            float4 v1 = *reinterpret_cast<const float4*>(vk + 1*256);
            float4 v2 = *reinterpret_cast<const float4*>(vk + 2*256);
            float4 v3 = *reinterpret_cast<const float4*>(vk + 3*256);
            o0[k16] = p0[ 0]*v0.x + p0[ 1]*v0.y + p0[ 2]*v0.z + p0[ 3]*v0.w
                    + p0[ 4]*v1.x + p0[ 5]*v1.y + p0[ 6]*v1.z + p0[ 7]*v1.w
                    + p0[ 8]*v2.x + p0[ 9]*v2.y + p0[10]*v2.z + p0[11]*v2.w
                    + p0[12]*v3.x + p0[13]*v3.y + p0[14]*v3.z + p0[15]*v3.w;
            o1[k16] = p1[ 0]*v0.x + p1[ 1]*v0.y + p1[ 2]*v0.z + p1[ 3]*v0.w
                    + p1[ 4]*v1.x + p1[ 5]*v1.y + p1[ 6]*v1.z + p1[ 7]*v1.w
                    + p1[ 8]*v2.x + p1[ 9]*v2.y + p1[10]*v2.z + p1[11]*v2.w
                    + p1[12]*v3.x + p1[13]*v3.y + p1[14]*v3.z + p1[15]*v3.w;
        }
        #pragma unroll
        for (int i = 0; i < 16; i++) { o0[i] += __shfl_xor(o0[i], 32); o1[i] += __shfl_xor(o1[i], 32); }
        if (l < 32) {
            float* rr = &sz[(w*32 + l)*68 + kh*16];
            #pragma unroll
            for (int i = 0; i < 4; i++) {
                *reinterpret_cast<float4*>(rr + i*4)      = make_float4(o0[4*i], o0[4*i+1], o0[4*i+2], o0[4*i+3]);
                *reinterpret_cast<float4*>(rr + 32 + i*4) = make_float4(o1[4*i], o1[4*i+1], o1[4*i+2], o1[4*i+3]);
            }
        }
    }
    __syncthreads();
    {
        int r = t >> 7, h = (t >> 5) & 3, k = t & 31;
        float acc = 0.f;
        #pragma unroll 8
        for (int l2 = 0; l2 < 32; l2++) acc += sz[(h*32 + l2)*68 + r*32 + k];
        heads[((size_t)h*ROWS + row0 + r)*KD + k] = acc * invs[r][h];
    }
}

// ---------------- K3: out-projection + residual + LN partials -------------
__global__ __launch_bounds__(256) void outproj_kernel(
    const float* __restrict__ heads, const float* __restrict__ Wot,
    const float* __restrict__ h32, float* __restrict__ outp,
    float* __restrict__ ps, float* __restrict__ pq)
{
    const int gid = blockIdx.x * 256 + threadIdx.x;
    const int row = gid >> 7, e = gid & 127;
    float acc = h32[gid];
    #pragma unroll
    for (int h = 0; h < HN; h++) {
        const float4* hp = reinterpret_cast<const float4*>(heads + ((size_t)h*ROWS + row)*KD);
        const float4* wp = reinterpret_cast<const float4*>(Wot + (size_t)e*EMB + h*KD);
        #pragma unroll
        for (int i = 0; i < 8; i++) {
            float4 a = hp[i], w = wp[i];
            acc += a.x*w.x + a.y*w.y + a.z*w.z + a.w*w.w;
        }
    }
    outp[gid] = acc;
    float s = acc, q = acc * acc;
    #pragma unroll
    for (int off = 32; off >= 1; off >>= 1) { s += __shfl_xor(s, off); q += __shfl_xor(q, off); }
    __shared__ float ls[4], lq[4];
    if ((threadIdx.x & 63) == 0) { ls[threadIdx.x >> 6] = s; lq[threadIdx.x >> 6] = q; }
    __syncthreads();
    if (threadIdx.x == 0) {
        ps[blockIdx.x] = ls[0] + ls[1] + ls[2] + ls[3];
        pq[blockIdx.x] = lq[0] + lq[1] + lq[2] + lq[3];
    }
}

// ---------------- K4/K7: finalize LN stats per batch ----------------------
__global__ __launch_bounds__(256) void stats_kernel(
    const float* __restrict__ ps, const float* __restrict__ pq,
    float* __restrict__ stats, int per_b, float M)
{
    int b = blockIdx.x, t = threadIdx.x;
    float s = 0.f, q = 0.f;
    for (int i = t; i < per_b; i += 256) { s += ps[b * per_b + i]; q += pq[b * per_b + i]; }
    #pragma unroll
    for (int off = 32; off >= 1; off >>= 1) { s += __shfl_xor(s, off); q += __shfl_xor(q, off); }
    __shared__ float ls[4], lq[4];
    if ((t & 63) == 0) { ls[t >> 6] = s; lq[t >> 6] = q; }
    __syncthreads();
    if (t == 0) {
        s = ls[0] + ls[1] + ls[2] + ls[3];
        q = lq[0] + lq[1] + lq[2] + lq[3];
        float mean = s / M;
        float var = (q - s * s / M) / (M - 1.0f);
        stats[2 * b] = mean;
        stats[2 * b + 1] = 1.0f / sqrtf(var + EPS);
    }
}

// ---------------- K6: LN1-apply + FF1+relu+FF2+residual + LN partials -----
// 8 rows per block (halves W1/W2 L2 re-read traffic vs 4 rows)
__global__ __launch_bounds__(256) void ff_kernel(
    const float* __restrict__ outp, const float* __restrict__ stats,
    const float* __restrict__ W1t, const float* __restrict__ W2t,
    float* __restrict__ outp2, float* __restrict__ ps, float* __restrict__ pq)
{
    __shared__ float xr[8][EMB];        // 4 KB
    __shared__ float hid[8][FFH];       // 16 KB
    __shared__ float rs[4], rq[4];
    const int t = threadIdx.x;
    const int row0 = blockIdx.x * 8;
    const int b = row0 >> 10;
    const float mean = stats[2*b], rstd = stats[2*b+1];

    {   // load 8x128 via float4, apply LN1
        float4 x4 = *reinterpret_cast<const float4*>(outp + (size_t)row0*EMB + t*4);
        int rr = t >> 5, cc = (t*4) & 127;
        xr[rr][cc+0] = (x4.x - mean)*rstd; xr[rr][cc+1] = (x4.y - mean)*rstd;
        xr[rr][cc+2] = (x4.z - mean)*rstd; xr[rr][cc+3] = (x4.w - mean)*rstd;
    }
    __syncthreads();

    {   // FF1: thread t owns hidden f = {t, t+256} for all 8 rows
        const float4* w0 = reinterpret_cast<const float4*>(W1t + (size_t)t * EMB);
        const float4* w1 = reinterpret_cast<const float4*>(W1t + (size_t)(t + 256) * EMB);
        float a[2][8] = {};
        #pragma unroll 8
        for (int i = 0; i < 32; i++) {
            float4 wa = w0[i], wb = w1[i];
            #pragma unroll
            for (int r = 0; r < 8; r++) {
                float4 x = *reinterpret_cast<const float4*>(&xr[r][i*4]);
                a[0][r] += wa.x*x.x + wa.y*x.y + wa.z*x.z + wa.w*x.w;
                a[1][r] += wb.x*x.x + wb.y*x.y + wb.z*x.z + wb.w*x.w;
            }
        }
        #pragma unroll
        for (int r = 0; r < 8; r++) {
            hid[r][t]       = fmaxf(a[0][r], 0.f);
            hid[r][t + 256] = fmaxf(a[1][r], 0.f);
        }
    }
    __syncthreads();

    // FF2: thread pair (e, half) splits the f-sum; all 8 rows share W row
    const int e = t >> 1, half = t & 1;
    float acc[8] = {};
    {
        const float4* wvp = reinterpret_cast<const float4*>(W2t + (size_t)e*FFH + half*256);
        #pragma unroll 8
        for (int i = 0; i < 64; i++) {
            float4 w = wvp[i];
            int fb = half*256 + i*4;
            #pragma unroll
            for (int r = 0; r < 8; r++) {
                float4 h4 = *reinterpret_cast<const float4*>(&hid[r][fb]);
                acc[r] += w.x*h4.x + w.y*h4.y + w.z*h4.z + w.w*h4.w;
            }
        }
    }
    #pragma unroll
    for (int r = 0; r < 8; r++) acc[r] += __shfl_xor(acc[r], 1);
    float s = 0.f, q = 0.f;
    if (half == 0) {
        #pragma unroll
        for (int r = 0; r < 8; r++) {
            float v = acc[r] + xr[r][e];
            outp2[(size_t)(row0 + r)*EMB + e] = v;
            s += v; q += v * v;
        }
    }
    #pragma unroll
    for (int off = 32; off >= 1; off >>= 1) { s += __shfl_xor(s, off); q += __shfl_xor(q, off); }
    if ((t & 63) == 0) { rs[t >> 6] = s; rq[t >> 6] = q; }
    __syncthreads();
    if (t == 0) {
        ps[blockIdx.x] = rs[0] + rs[1] + rs[2] + rs[3];
        pq[blockIdx.x] = rq[0] + rq[1] + rq[2] + rq[3];
    }
}

// ---------------- K8: apply LN2 -> float out ------------------------------
__global__ __launch_bounds__(256) void final_kernel(
    const float* __restrict__ in, const float* __restrict__ stats, float* __restrict__ out)
{
    int gid = blockIdx.x * 256 + threadIdx.x;
    int b = gid >> 17;
    out[gid] = (in[gid] - stats[2 * b]) * stats[2 * b + 1];
}

// ---------------- K9: input2 passthrough -> float out ---------------------
__global__ __launch_bounds__(256) void copy2_kernel(
    const void* __restrict__ in, uint4* __restrict__ out, const int* __restrict__ flags)
{
    const int f_2 = flags[1];
    size_t gid = (size_t)blockIdx.x * 256 + threadIdx.x;
    if (f_2) {
        out[gid] = ((const uint4*)in)[gid];
    } else {
        const bf16* p = (const bf16*)in + gid * 4;
        float4 v = { b2f(p[0]), b2f(p[1]), b2f(p[2]), b2f(p[3]) };
        out[gid] = *(const uint4*)&v;
    }
}

extern "C" void kernel_launch(void* const* d_in, const int* in_sizes, int n_in,
                              void* d_out, int out_size, void* d_ws, size_t ws_size,
                              hipStream_t stream)
{
    const void* input1 = d_in[0];
    const void* input2 = d_in[1];
    const void* Wq  = d_in[2];
    const void* Wk  = d_in[3];
    const void* Wv  = d_in[4];
    const void* Wo  = d_in[5];
    const void* Ws1 = d_in[6];
    const void* bs1 = d_in[7];
    const void* Ws2 = d_in[8];
    const void* bs2 = d_in[9];
    const void* Wf1 = d_in[10];
    const void* Wf2 = d_in[11];

    float* out1 = (float*)d_out;                       // [ROWS*EMB] f32
    float* out2 = (float*)d_out + (size_t)ROWS * EMB;  // input2 passthrough (written LAST)

    char* sb = (char*)out2;
    float* Q32   = (float*)(sb);                       // 4 MB
    float* Kt32  = (float*)(sb + (4u  << 20));         // 4 MB
    float* Vt32  = (float*)(sb + (8u  << 20));         // 4 MB
    float* heads = (float*)(sb + (12u << 20));         // 4 MB
    float* outp  = (float*)(sb + (16u << 20));         // 4 MB
    float* outp2 = (float*)(sb + (20u << 20));         // 4 MB
    float* h32   = (float*)(sb + (24u << 20));         // 4 MB
    float* Wt    = (float*)(sb + (28u << 20));                 // 192 KB
    float* Wot   = (float*)(sb + (28u << 20) + 0x30000);       // 64 KB
    float* W1t   = (float*)(sb + (28u << 20) + 0x40000);       // 256 KB
    float* W2t   = (float*)(sb + (28u << 20) + 0x80000);       // 256 KB
    float* mlp32 = (float*)(sb + (28u << 20) + 0xC0000);       // 432 B
    float* ps    = (float*)(sb + (28u << 20) + 0xC1000);       // 16 KB
    float* pq    = (float*)(sb + (28u << 20) + 0xC5000);       // 16 KB
    float* stats = (float*)(sb + (28u << 20) + 0xC9000);
    float* stats2= (float*)(sb + (28u << 20) + 0xC9100);
    int*   flags = (int*)  (sb + (28u << 20) + 0xC9200);

    const float M = (float)(SEQ * EMB);                // 131072 per batch

    hipLaunchKernelGGL(detect_kernel, dim3(9), dim3(256), 0, stream,
                       (const unsigned int*)input1, (const unsigned int*)input2,
                       (const unsigned int*)Wq, (const unsigned int*)Wk,
                       (const unsigned int*)Wv, (const unsigned int*)Wo,
                       (const unsigned int*)Ws1, (const unsigned int*)bs1,
                       (const unsigned int*)Ws2, (const unsigned int*)bs2,
                       (const unsigned int*)Wf1, (const unsigned int*)Wf2, flags);
    hipLaunchKernelGGL(convert_kernel, dim3(1793), dim3(256), 0, stream,
                       input1, Wq, Wk, Wv, Wo, Ws1, bs1, Ws2, bs2, Wf1, Wf2,
                       h32, Wt, Wot, W1t, W2t, mlp32, flags);
    hipLaunchKernelGGL(qkv_kernel, dim3(768), dim3(256), 0, stream,
                       h32, Wt, Q32, Kt32, Vt32);
    hipLaunchKernelGGL(attn_kernel, dim3(ROWS / 2), dim3(256), 0, stream,
                       Q32, Kt32, Vt32, input2, mlp32, heads, flags);
    hipLaunchKernelGGL(outproj_kernel, dim3(ROWS * EMB / 256), dim3(256), 0, stream,
                       heads, Wot, h32, outp, ps, pq);
    hipLaunchKernelGGL(stats_kernel, dim3(NB), dim3(256), 0, stream,
                       ps, pq, stats, 512, M);
    hipLaunchKernelGGL(ff_kernel, dim3(ROWS / 8), dim3(256), 0, stream,
                       outp, stats, W1t, W2t, outp2, ps, pq);
    hipLaunchKernelGGL(stats_kernel, dim3(NB), dim3(256), 0, stream,
                       ps, pq, stats2, 128, M);
    hipLaunchKernelGGL(final_kernel, dim3(ROWS * EMB / 256), dim3(256), 0, stream,
                       outp2, stats2, out1);
    hipLaunchKernelGGL(copy2_kernel, dim3(ROWS * SEQ * HN / 4 / 256), dim3(256), 0, stream,
                       input2, (uint4*)out2, flags);
}

// Round 8
// 620.309 us; speedup vs baseline: 1.3524x; 1.3524x over previous
//
#include <hip/hip_runtime.h>
#include <hip/hip_bf16.h>

typedef __hip_bfloat16 bf16;

static constexpr int HN  = 4;     // heads
static constexpr int NB  = 8;     // batch
static constexpr int SEQ = 1024;  // nodes
static constexpr int EMB = 128;
static constexpr int KD  = 32;
static constexpr int FFH = 512;
static constexpr int ROWS = NB * SEQ;       // 8192
static constexpr float EPS = 1e-5f;

__device__ __forceinline__ float b2f(bf16 x){ return __bfloat162float(x); }

// dtype-dispatched load: flag==1 -> buffer is float32, else bf16
__device__ __forceinline__ float ldx(const void* p, size_t i, int f32){
    return f32 ? ((const float*)p)[i] : b2f(((const bf16*)p)[i]);
}

// ---------------- K0: per-input dtype detector ----------------------------
__device__ __forceinline__ float probe_max(const unsigned int* w, int nwords, int t){
    float mx = 0.f;
    for (int i = t; i < nwords; i += 256) {
        float v = fabsf(__uint_as_float(w[i] << 16));
        if (!(v <= 1e4f)) v = 1e30f;
        mx = fmaxf(mx, v);
    }
    return mx;
}

// flags: 0=input1 1=input2 2=Wq 3=Wk 4=Wv 5=Wo 6=tinyMLP 7=Wff1 8=Wff2
__global__ __launch_bounds__(256) void detect_kernel(
    const unsigned int* in1, const unsigned int* in2,
    const unsigned int* wq,  const unsigned int* wk, const unsigned int* wv,
    const unsigned int* wo,  const unsigned int* ws1, const unsigned int* bs1,
    const unsigned int* ws2, const unsigned int* bs2,
    const unsigned int* wf1, const unsigned int* wf2, int* __restrict__ flags)
{
    __shared__ float red[4];
    const int b = blockIdx.x, t = threadIdx.x;
    float mx = 0.f;
    if      (b == 0) mx = probe_max(in1, 4096, t);
    else if (b == 1) mx = probe_max(in2, 4096, t);
    else if (b == 2) mx = probe_max(wq, 4096, t);
    else if (b == 3) mx = probe_max(wk, 4096, t);
    else if (b == 4) mx = probe_max(wv, 4096, t);
    else if (b == 5) mx = probe_max(wo, 4096, t);
    else if (b == 6) {
        mx = fmaxf(probe_max(ws1, 32, t), probe_max(bs1, 4, t));
        mx = fmaxf(mx, fmaxf(probe_max(ws2, 16, t), probe_max(bs2, 2, t)));
    }
    else if (b == 7) mx = probe_max(wf1, 4096, t);
    else             mx = probe_max(wf2, 4096, t);

    #pragma unroll
    for (int off = 32; off >= 1; off >>= 1) mx = fmaxf(mx, __shfl_xor(mx, off));
    if ((t & 63) == 0) red[t >> 6] = mx;
    __syncthreads();
    if (t == 0) {
        mx = fmaxf(fmaxf(red[0], red[1]), fmaxf(red[2], red[3]));
        flags[b] = (mx > 1e4f) ? 1 : 0;
    }
}

// ---------------- K0b: resolve dtypes + transpose weights ONCE ------------
__global__ __launch_bounds__(256) void convert_kernel(
    const void* in1, const void* Wq, const void* Wk, const void* Wv, const void* Wo,
    const void* Ws1, const void* bs1, const void* Ws2, const void* bs2,
    const void* Wf1, const void* Wf2,
    float* __restrict__ h32, float* __restrict__ Wt, float* __restrict__ Wot,
    float* __restrict__ W1t, float* __restrict__ W2t, float* __restrict__ mlp32,
    const int* __restrict__ flags)
{
    int gid = blockIdx.x * 256 + threadIdx.x;
    if (gid < 262144) {                         // input1 -> f32, 4 elems/thread
        if (flags[0]) {
            ((float4*)h32)[gid] = ((const float4*)in1)[gid];
        } else {
            const bf16* p = (const bf16*)in1 + (size_t)gid * 4;
            h32[gid*4+0] = b2f(p[0]); h32[gid*4+1] = b2f(p[1]);
            h32[gid*4+2] = b2f(p[2]); h32[gid*4+3] = b2f(p[3]);
        }
        return;
    }
    int r = gid - 262144;
    if (r < 49152) {                            // Wt[mat][h][k][e] = W[h][e][k]
        int mat = r >> 14, q = r & 16383;
        int h = q >> 12, k = (q >> 7) & 31, e = q & 127;
        const void* W = (mat == 0) ? Wq : (mat == 1) ? Wk : Wv;
        Wt[r] = ldx(W, (size_t)(h*EMB + e)*KD + k, flags[2+mat]);
        return;
    }
    r -= 49152;
    if (r < 16384) {                            // Wot[e][hk] = Wo[hk][e]
        int e = r >> 7, hk = r & 127;
        Wot[r] = ldx(Wo, (size_t)hk*EMB + e, flags[5]);
        return;
    }
    r -= 16384;
    if (r < 65536) {                            // W1t[f][e] = Wf1[e][f]
        int f = r >> 7, e = r & 127;
        W1t[r] = ldx(Wf1, (size_t)e*FFH + f, flags[7]);
        return;
    }
    r -= 65536;
    if (r < 65536) {                            // W2t[e][f] = Wf2[f][e]
        int e = r >> 9, f = r & 511;
        W2t[r] = ldx(Wf2, (size_t)f*EMB + e, flags[8]);
        return;
    }
    r -= 65536;
    if (r < 108) {
        const int fm = flags[6];
        float v;
        if (r < 64)       { int j = r >> 3, i = r & 7; v = ldx(Ws1, i*8 + j, fm); }
        else if (r < 72)  v = ldx(bs1, r - 64, fm);
        else if (r < 104) v = ldx(Ws2, r - 72, fm);    // w2[j][c] row-major kept
        else              v = ldx(bs2, r - 104, fm);
        mlp32[r] = v;
    }
}

// ---------------- K1: QKV projection, LDS-tiled GEMM ----------------------
// Outputs (all f32): Q32[h][row][k], Kt32[h][b][k][n], Vt32[h][b][k][n]
__global__ __launch_bounds__(256) void qkv_kernel(
    const float* __restrict__ h32, const float* __restrict__ Wt,
    float* __restrict__ Q32, float* __restrict__ Kt32, float* __restrict__ Vt32)
{
    __shared__ float hl[128 * 132];
    const int t   = threadIdx.x;
    const int bid = blockIdx.x;
    const int mat = bid >> 8;                   // 768 = 3 * 4 * 64
    const int hh  = (bid >> 6) & 3;
    const int rt  = bid & 63;
    const int row0 = rt * 128;

    #pragma unroll
    for (int i = 0; i < 16; i++) {
        int idx = t + 256 * i;
        int r  = idx >> 5;
        int e4 = (idx & 31) * 4;
        float4 v = *reinterpret_cast<const float4*>(h32 + (size_t)(row0 + r) * EMB + e4);
        *reinterpret_cast<float4*>(&hl[r * 132 + e4]) = v;
    }
    __syncthreads();

    const int rq = t >> 3;
    const int kq = t & 7;
    const float* wbase = Wt + ((size_t)(mat * HN + hh) * KD + kq * 4) * EMB;
    float acc[4][4] = {};
    #pragma unroll 4
    for (int eq = 0; eq < 32; eq++) {
        float4 a0 = *reinterpret_cast<const float4*>(&hl[(rq*4+0)*132 + eq*4]);
        float4 a1 = *reinterpret_cast<const float4*>(&hl[(rq*4+1)*132 + eq*4]);
        float4 a2 = *reinterpret_cast<const float4*>(&hl[(rq*4+2)*132 + eq*4]);
        float4 a3 = *reinterpret_cast<const float4*>(&hl[(rq*4+3)*132 + eq*4]);
        float4 w0 = *reinterpret_cast<const float4*>(wbase + 0*EMB + eq*4);
        float4 w1 = *reinterpret_cast<const float4*>(wbase + 1*EMB + eq*4);
        float4 w2 = *reinterpret_cast<const float4*>(wbase + 2*EMB + eq*4);
        float4 w3 = *reinterpret_cast<const float4*>(wbase + 3*EMB + eq*4);
        #pragma unroll
        for (int kk = 0; kk < 4; kk++) {
            float4 w = (kk==0)?w0:(kk==1)?w1:(kk==2)?w2:w3;
            acc[0][kk] += a0.x*w.x + a0.y*w.y + a0.z*w.z + a0.w*w.w;
            acc[1][kk] += a1.x*w.x + a1.y*w.y + a1.z*w.z + a1.w*w.w;
            acc[2][kk] += a2.x*w.x + a2.y*w.y + a2.z*w.z + a2.w*w.w;
            acc[3][kk] += a3.x*w.x + a3.y*w.y + a3.z*w.z + a3.w*w.w;
        }
    }

    if (mat == 0) {
        #pragma unroll
        for (int r = 0; r < 4; r++) {
            float4 v = { acc[r][0], acc[r][1], acc[r][2], acc[r][3] };
            *reinterpret_cast<float4*>(Q32 + ((size_t)hh*ROWS + row0 + rq*4 + r)*KD + kq*4) = v;
        }
    } else {
        float* out = (mat == 1) ? Kt32 : Vt32;
        int bb = row0 >> 10;
        int n0 = (row0 & 1023) + rq * 4;
        #pragma unroll
        for (int kk = 0; kk < 4; kk++) {
            float4 v = { acc[0][kk], acc[1][kk], acc[2][kk], acc[3][kk] };
            *reinterpret_cast<float4*>(out + ((size_t)(hh*NB + bb)*KD + kq*4 + kk)*SEQ + n0) = v;
        }
    }
}

// Phase-1 score chunk: k in [KC*16, KC*16+16). KC=0 initializes the score
// planes; KC=1 read-modify-writes them (same-thread RAW through LDS, ordered).
// Halves the q-register working set (32 live instead of 64).
#define P1_CHUNK(KC)                                                           \
    {                                                                          \
        float q0[16], q1[16];                                                  \
        _Pragma("unroll")                                                      \
        for (int i = 0; i < 4; i++) {                                          \
            float4 a = *reinterpret_cast<const float4*>(&qld[w][0][(KC)*16 + i*4]); \
            float4 c = *reinterpret_cast<const float4*>(&qld[w][1][(KC)*16 + i*4]); \
            q0[4*i+0]=a.x; q0[4*i+1]=a.y; q0[4*i+2]=a.z; q0[4*i+3]=a.w;        \
            q1[4*i+0]=c.x; q1[4*i+1]=c.y; q1[4*i+2]=c.z; q1[4*i+3]=c.w;        \
        }                                                                      \
        _Pragma("unroll 2")                                                    \
        for (int mc = 0; mc < 4; mc++) {                                       \
            const int m = mc*256 + l*4;                                        \
            float4 s0, s1;                                                     \
            if (KC) {                                                          \
                s0 = *reinterpret_cast<const float4*>(&sz[(w*2+0)*SEQ + m]);   \
                s1 = *reinterpret_cast<const float4*>(&sz[(w*2+1)*SEQ + m]);   \
            } else {                                                           \
                s0 = make_float4(0.f,0.f,0.f,0.f);                             \
                s1 = make_float4(0.f,0.f,0.f,0.f);                             \
            }                                                                  \
            _Pragma("unroll")                                                  \
            for (int k = 0; k < 16; k++) {                                     \
                float4 kv = *reinterpret_cast<const float4*>(kb + (size_t)((KC)*16 + k)*SEQ + m); \
                s0.x += q0[k]*kv.x; s0.y += q0[k]*kv.y; s0.z += q0[k]*kv.z; s0.w += q0[k]*kv.w; \
                s1.x += q1[k]*kv.x; s1.y += q1[k]*kv.y; s1.z += q1[k]*kv.z; s1.w += q1[k]*kv.w; \
            }                                                                  \
            *reinterpret_cast<float4*>(&sz[(w*2+0)*SEQ + m]) = s0;             \
            *reinterpret_cast<float4*>(&sz[(w*2+1)*SEQ + m]) = s1;             \
        }                                                                      \
    }

// Phase-2 tiny-MLP row body (all-static indices).
#define MLP_ROW(R, V0, V1, V2, V3)                                            \
    {                                                                          \
        float x0[8], x1[8], x2[8], x3[8];                                      \
        _Pragma("unroll")                                                      \
        for (int h = 0; h < 4; h++) {                                          \
            float4 s4 = *reinterpret_cast<const float4*>(&sz[(h*2+(R))*SEQ + m0]); \
            x0[h]=s4.x; x1[h]=s4.y; x2[h]=s4.z; x3[h]=s4.w;                    \
        }                                                                      \
        x0[4]=(V0).x; x1[4]=(V0).y; x2[4]=(V0).z; x3[4]=(V0).w;                \
        x0[5]=(V1).x; x1[5]=(V1).y; x2[5]=(V1).z; x3[5]=(V1).w;                \
        x0[6]=(V2).x; x1[6]=(V2).y; x2[6]=(V2).z; x3[6]=(V2).w;                \
        x0[7]=(V3).x; x1[7]=(V3).y; x2[7]=(V3).z; x3[7]=(V3).w;                \
        float zc[4][4];                                                        \
        _Pragma("unroll")                                                      \
        for (int m = 0; m < 4; m++) {                                          \
            _Pragma("unroll")                                                  \
            for (int c = 0; c < 4; c++) zc[m][c] = wm[104 + c];                \
        }                                                                      \
        _Pragma("unroll")                                                      \
        for (int j = 0; j < 8; j++) {                                          \
            float4 wa = *reinterpret_cast<const float4*>(&wm[j*8]);            \
            float4 wb = *reinterpret_cast<const float4*>(&wm[j*8+4]);          \
            float b1j = wm[64 + j];                                            \
            float4 w2v = *reinterpret_cast<const float4*>(&wm[72 + j*4]);      \
            float y0 = b1j + x0[0]*wa.x + x0[1]*wa.y + x0[2]*wa.z + x0[3]*wa.w \
                           + x0[4]*wb.x + x0[5]*wb.y + x0[6]*wb.z + x0[7]*wb.w;\
            float y1 = b1j + x1[0]*wa.x + x1[1]*wa.y + x1[2]*wa.z + x1[3]*wa.w \
                           + x1[4]*wb.x + x1[5]*wb.y + x1[6]*wb.z + x1[7]*wb.w;\
            float y2 = b1j + x2[0]*wa.x + x2[1]*wa.y + x2[2]*wa.z + x2[3]*wa.w \
                           + x2[4]*wb.x + x2[5]*wb.y + x2[6]*wb.z + x2[7]*wb.w;\
            float y3 = b1j + x3[0]*wa.x + x3[1]*wa.y + x3[2]*wa.z + x3[3]*wa.w \
                           + x3[4]*wb.x + x3[5]*wb.y + x3[6]*wb.z + x3[7]*wb.w;\
            y0 = fmaxf(y0, 0.f); y1 = fmaxf(y1, 0.f);                          \
            y2 = fmaxf(y2, 0.f); y3 = fmaxf(y3, 0.f);                          \
            zc[0][0] += y0*w2v.x; zc[0][1] += y0*w2v.y; zc[0][2] += y0*w2v.z; zc[0][3] += y0*w2v.w; \
            zc[1][0] += y1*w2v.x; zc[1][1] += y1*w2v.y; zc[1][2] += y1*w2v.z; zc[1][3] += y1*w2v.w; \
            zc[2][0] += y2*w2v.x; zc[2][1] += y2*w2v.y; zc[2][2] += y2*w2v.z; zc[2][3] += y2*w2v.w; \
            zc[3][0] += y3*w2v.x; zc[3][1] += y3*w2v.y; zc[3][2] += y3*w2v.z; zc[3][3] += y3*w2v.w; \
        }                                                                      \
        _Pragma("unroll")                                                      \
        for (int c = 0; c < 4; c++)                                            \
            *reinterpret_cast<float4*>(&sz[(c*2 + (R))*SEQ + m0]) =            \
                make_float4(zc[0][c], zc[1][c], zc[2][c], zc[3][c]);           \
    }

// ---------------- K2: fused attention, 2 rows per block -------------------
// (256,2): VGPR cap ~128 (the (256,3) variant capped at 84 -> 630 MB spill,
// observed r4/r6/r7). True demand ~100 after Phase-1 k-split -> no spill.
__global__ __launch_bounds__(256, 2) void attn_kernel(
    const float* __restrict__ Q32, const float* __restrict__ Kt32,
    const float* __restrict__ Vt32, const void* __restrict__ in2,
    const float* __restrict__ mlp, float* __restrict__ heads,
    const int* __restrict__ flags)
{
    __shared__ float sz[8704];          // 8 planes [1024] ∪ red[4][32][68]
    __shared__ float qld[HN][2][KD];
    __shared__ float wm[108];
    __shared__ float invs[2][HN];

    const int t = threadIdx.x;
    // XCD swizzle: contiguous 512-block chunk (one batch) per XCD.
    const int wg   = (blockIdx.x & 7) * 512 + (blockIdx.x >> 3);
    const int row0 = wg * 2;
    const int b    = row0 >> 10;
    const int n0   = row0 & (SEQ - 1);
    const int m0   = t * 4;
    const int f2   = flags[1];
    const int w    = t >> 6, l = t & 63;

    { int h = t >> 6, r = (t >> 5) & 1, k = t & 31;
      qld[h][r][k] = Q32[((size_t)h*ROWS + row0 + r)*KD + k]; }
    if (t < 108) wm[t] = mlp[t];

    // in2 prefetch into NAMED float4 scalars; issued early, consumed Phase 2.
    auto ld2 = [&](int c, int r) -> float4 {
        size_t base = ((size_t)(c*NB + b)*SEQ + (n0 + r))*SEQ + m0;
        if (f2) return *reinterpret_cast<const float4*>((const float*)in2 + base);
        ushort4 u = *reinterpret_cast<const ushort4*>((const ushort*)in2 + base);
        return make_float4(
            __uint_as_float((unsigned)u.x << 16), __uint_as_float((unsigned)u.y << 16),
            __uint_as_float((unsigned)u.z << 16), __uint_as_float((unsigned)u.w << 16));
    };
    float4 iA0 = ld2(0,0), iA1 = ld2(1,0), iA2 = ld2(2,0), iA3 = ld2(3,0);
    float4 iB0 = ld2(0,1), iB1 = ld2(1,1), iB2 = ld2(2,1), iB3 = ld2(3,1);
    __syncthreads();

    // ---- Phase 1: wave w = head w; two k-chunks (q regs 32, not 64) ----
    {
        const float* kb = Kt32 + ((size_t)(w*NB + b)*KD)*SEQ;
        P1_CHUNK(0)
        P1_CHUNK(1)
    }
    __syncthreads();

    // ---- Phase 2: tiny MLP, two explicit row bodies (all-static indices) ----
    MLP_ROW(0, iA0, iA1, iA2, iA3)
    MLP_ROW(1, iB0, iB1, iB2, iB3)
    __syncthreads();

    // ---- Phase 3: wave w = head w softmax; lane l owns m in {4l+256i} ----
    float p0[16], p1[16];
    {
        #pragma unroll
        for (int i = 0; i < 4; i++) {
            float4 a = *reinterpret_cast<const float4*>(&sz[(w*2+0)*SEQ + i*256 + l*4]);
            float4 c = *reinterpret_cast<const float4*>(&sz[(w*2+1)*SEQ + i*256 + l*4]);
            p0[4*i+0]=a.x; p0[4*i+1]=a.y; p0[4*i+2]=a.z; p0[4*i+3]=a.w;
            p1[4*i+0]=c.x; p1[4*i+1]=c.y; p1[4*i+2]=c.z; p1[4*i+3]=c.w;
        }
        float mx0 = -1e30f, mx1 = -1e30f;
        #pragma unroll
        for (int i = 0; i < 16; i++) { mx0 = fmaxf(mx0, p0[i]); mx1 = fmaxf(mx1, p1[i]); }
        #pragma unroll
        for (int off = 32; off >= 1; off >>= 1) {
            mx0 = fmaxf(mx0, __shfl_xor(mx0, off));
            mx1 = fmaxf(mx1, __shfl_xor(mx1, off));
        }
        float s0 = 0.f, s1 = 0.f;
        #pragma unroll
        for (int i = 0; i < 16; i++) {
            p0[i] = __expf(p0[i] - mx0); s0 += p0[i];
            p1[i] = __expf(p1[i] - mx1); s1 += p1[i];
        }
        #pragma unroll
        for (int off = 32; off >= 1; off >>= 1) { s0 += __shfl_xor(s0, off); s1 += __shfl_xor(s1, off); }
        if (l == 0) { invs[0][w] = 1.f / s0; invs[1][w] = 1.f / s1; }
    }
    __syncthreads();                     // z consumed -> sz reusable as red

    // ---- Phase 4: PV in two k-halves (16 accs/row) ----
    #pragma unroll 1
    for (int kh = 0; kh < 2; kh++) {
        float o0[16], o1[16];
        #pragma unroll
        for (int i = 0; i < 16; i++) { o0[i] = 0.f; o1[i] = 0.f; }
        const float* vb = Vt32 + ((size_t)(w*NB + b)*KD + kh*16)*SEQ + l*4;
        #pragma unroll
        for (int k16 = 0; k16 < 16; k16++) {
            const float* vk = vb + (size_t)k16*SEQ;
            float4 v0 = *reinterpret_cast<const float4*>(vk + 0*256);
            float4 v1 = *reinterpret_cast<const float4*>(vk + 1*256);
            float4 v2 = *reinterpret_cast<const float4*>(vk + 2*256);
            float4 v3 = *reinterpret_cast<const float4*>(vk + 3*256);
            o0[k16] = p0[ 0]*v0.x + p0[ 1]*v0.y + p0[ 2]*v0.z + p0[ 3]*v0.w
                    + p0[ 4]*v1.x + p0[ 5]*v1.y + p0[ 6]*v1.z + p0[ 7]*v1.w
                    + p0[ 8]*v2.x + p0[ 9]*v2.y + p0[10]*v2.z + p0[11]*v2.w
                    + p0[12]*v3.x + p0[13]*v3.y + p0[14]*v3.z + p0[15]*v3.w;
            o1[k16] = p1[ 0]*v0.x + p1[ 1]*v0.y + p1[ 2]*v0.z + p1[ 3]*v0.w
                    + p1[ 4]*v1.x + p1[ 5]*v1.y + p1[ 6]*v1.z + p1[ 7]*v1.w
                    + p1[ 8]*v2.x + p1[ 9]*v2.y + p1[10]*v2.z + p1[11]*v2.w
                    + p1[12]*v3.x + p1[13]*v3.y + p1[14]*v3.z + p1[15]*v3.w;
        }
        #pragma unroll
        for (int i = 0; i < 16; i++) { o0[i] += __shfl_xor(o0[i], 32); o1[i] += __shfl_xor(o1[i], 32); }
        if (l < 32) {
            float* rr = &sz[(w*32 + l)*68 + kh*16];
            #pragma unroll
            for (int i = 0; i < 4; i++) {
                *reinterpret_cast<float4*>(rr + i*4)      = make_float4(o0[4*i], o0[4*i+1], o0[4*i+2], o0[4*i+3]);
                *reinterpret_cast<float4*>(rr + 32 + i*4) = make_float4(o1[4*i], o1[4*i+1], o1[4*i+2], o1[4*i+3]);
            }
        }
    }
    __syncthreads();
    {
        int r = t >> 7, h = (t >> 5) & 3, k = t & 31;
        float acc = 0.f;
        #pragma unroll 8
        for (int l2 = 0; l2 < 32; l2++) acc += sz[(h*32 + l2)*68 + r*32 + k];
        heads[((size_t)h*ROWS + row0 + r)*KD + k] = acc * invs[r][h];
    }
}

// ---------------- K3: out-projection + residual + LN partials -------------
__global__ __launch_bounds__(256) void outproj_kernel(
    const float* __restrict__ heads, const float* __restrict__ Wot,
    const float* __restrict__ h32, float* __restrict__ outp,
    float* __restrict__ ps, float* __restrict__ pq)
{
    const int gid = blockIdx.x * 256 + threadIdx.x;
    const int row = gid >> 7, e = gid & 127;
    float acc = h32[gid];
    #pragma unroll
    for (int h = 0; h < HN; h++) {
        const float4* hp = reinterpret_cast<const float4*>(heads + ((size_t)h*ROWS + row)*KD);
        const float4* wp = reinterpret_cast<const float4*>(Wot + (size_t)e*EMB + h*KD);
        #pragma unroll
        for (int i = 0; i < 8; i++) {
            float4 a = hp[i], w = wp[i];
            acc += a.x*w.x + a.y*w.y + a.z*w.z + a.w*w.w;
        }
    }
    outp[gid] = acc;
    float s = acc, q = acc * acc;
    #pragma unroll
    for (int off = 32; off >= 1; off >>= 1) { s += __shfl_xor(s, off); q += __shfl_xor(q, off); }
    __shared__ float ls[4], lq[4];
    if ((threadIdx.x & 63) == 0) { ls[threadIdx.x >> 6] = s; lq[threadIdx.x >> 6] = q; }
    __syncthreads();
    if (threadIdx.x == 0) {
        ps[blockIdx.x] = ls[0] + ls[1] + ls[2] + ls[3];
        pq[blockIdx.x] = lq[0] + lq[1] + lq[2] + lq[3];
    }
}

// ---------------- K4/K7: finalize LN stats per batch ----------------------
__global__ __launch_bounds__(256) void stats_kernel(
    const float* __restrict__ ps, const float* __restrict__ pq,
    float* __restrict__ stats, int per_b, float M)
{
    int b = blockIdx.x, t = threadIdx.x;
    float s = 0.f, q = 0.f;
    for (int i = t; i < per_b; i += 256) { s += ps[b * per_b + i]; q += pq[b * per_b + i]; }
    #pragma unroll
    for (int off = 32; off >= 1; off >>= 1) { s += __shfl_xor(s, off); q += __shfl_xor(q, off); }
    __shared__ float ls[4], lq[4];
    if ((t & 63) == 0) { ls[t >> 6] = s; lq[t >> 6] = q; }
    __syncthreads();
    if (t == 0) {
        s = ls[0] + ls[1] + ls[2] + ls[3];
        q = lq[0] + lq[1] + lq[2] + lq[3];
        float mean = s / M;
        float var = (q - s * s / M) / (M - 1.0f);
        stats[2 * b] = mean;
        stats[2 * b + 1] = 1.0f / sqrtf(var + EPS);
    }
}

// ---------------- K6: LN1-apply + FF1+relu+FF2+residual + LN partials -----
// 8 rows per block (halves W1/W2 L2 re-read traffic vs 4 rows)
__global__ __launch_bounds__(256) void ff_kernel(
    const float* __restrict__ outp, const float* __restrict__ stats,
    const float* __restrict__ W1t, const float* __restrict__ W2t,
    float* __restrict__ outp2, float* __restrict__ ps, float* __restrict__ pq)
{
    __shared__ float xr[8][EMB];        // 4 KB
    __shared__ float hid[8][FFH];       // 16 KB
    __shared__ float rs[4], rq[4];
    const int t = threadIdx.x;
    const int row0 = blockIdx.x * 8;
    const int b = row0 >> 10;
    const float mean = stats[2*b], rstd = stats[2*b+1];

    {   // load 8x128 via float4, apply LN1
        float4 x4 = *reinterpret_cast<const float4*>(outp + (size_t)row0*EMB + t*4);
        int rr = t >> 5, cc = (t*4) & 127;
        xr[rr][cc+0] = (x4.x - mean)*rstd; xr[rr][cc+1] = (x4.y - mean)*rstd;
        xr[rr][cc+2] = (x4.z - mean)*rstd; xr[rr][cc+3] = (x4.w - mean)*rstd;
    }
    __syncthreads();

    {   // FF1: thread t owns hidden f = {t, t+256} for all 8 rows
        const float4* w0 = reinterpret_cast<const float4*>(W1t + (size_t)t * EMB);
        const float4* w1 = reinterpret_cast<const float4*>(W1t + (size_t)(t + 256) * EMB);
        float a[2][8] = {};
        #pragma unroll 8
        for (int i = 0; i < 32; i++) {
            float4 wa = w0[i], wb = w1[i];
            #pragma unroll
            for (int r = 0; r < 8; r++) {
                float4 x = *reinterpret_cast<const float4*>(&xr[r][i*4]);
                a[0][r] += wa.x*x.x + wa.y*x.y + wa.z*x.z + wa.w*x.w;
                a[1][r] += wb.x*x.x + wb.y*x.y + wb.z*x.z + wb.w*x.w;
            }
        }
        #pragma unroll
        for (int r = 0; r < 8; r++) {
            hid[r][t]       = fmaxf(a[0][r], 0.f);
            hid[r][t + 256] = fmaxf(a[1][r], 0.f);
        }
    }
    __syncthreads();

    // FF2: thread pair (e, half) splits the f-sum; all 8 rows share W row
    const int e = t >> 1, half = t & 1;
    float acc[8] = {};
    {
        const float4* wvp = reinterpret_cast<const float4*>(W2t + (size_t)e*FFH + half*256);
        #pragma unroll 8
        for (int i = 0; i < 64; i++) {
            float4 w = wvp[i];
            int fb = half*256 + i*4;
            #pragma unroll
            for (int r = 0; r < 8; r++) {
                float4 h4 = *reinterpret_cast<const float4*>(&hid[r][fb]);
                acc[r] += w.x*h4.x + w.y*h4.y + w.z*h4.z + w.w*h4.w;
            }
        }
    }
    #pragma unroll
    for (int r = 0; r < 8; r++) acc[r] += __shfl_xor(acc[r], 1);
    float s = 0.f, q = 0.f;
    if (half == 0) {
        #pragma unroll
        for (int r = 0; r < 8; r++) {
            float v = acc[r] + xr[r][e];
            outp2[(size_t)(row0 + r)*EMB + e] = v;
            s += v; q += v * v;
        }
    }
    #pragma unroll
    for (int off = 32; off >= 1; off >>= 1) { s += __shfl_xor(s, off); q += __shfl_xor(q, off); }
    if ((t & 63) == 0) { rs[t >> 6] = s; rq[t >> 6] = q; }
    __syncthreads();
    if (t == 0) {
        ps[blockIdx.x] = rs[0] + rs[1] + rs[2] + rs[3];
        pq[blockIdx.x] = rq[0] + rq[1] + rq[2] + rq[3];
    }
}

// ---------------- K8: apply LN2 -> float out ------------------------------
__global__ __launch_bounds__(256) void final_kernel(
    const float* __restrict__ in, const float* __restrict__ stats, float* __restrict__ out)
{
    int gid = blockIdx.x * 256 + threadIdx.x;
    int b = gid >> 17;
    out[gid] = (in[gid] - stats[2 * b]) * stats[2 * b + 1];
}

// ---------------- K9: input2 passthrough -> float out ---------------------
__global__ __launch_bounds__(256) void copy2_kernel(
    const void* __restrict__ in, uint4* __restrict__ out, const int* __restrict__ flags)
{
    const int f_2 = flags[1];
    size_t gid = (size_t)blockIdx.x * 256 + threadIdx.x;
    if (f_2) {
        out[gid] = ((const uint4*)in)[gid];
    } else {
        const bf16* p = (const bf16*)in + gid * 4;
        float4 v = { b2f(p[0]), b2f(p[1]), b2f(p[2]), b2f(p[3]) };
        out[gid] = *(const uint4*)&v;
    }
}

extern "C" void kernel_launch(void* const* d_in, const int* in_sizes, int n_in,
                              void* d_out, int out_size, void* d_ws, size_t ws_size,
                              hipStream_t stream)
{
    const void* input1 = d_in[0];
    const void* input2 = d_in[1];
    const void* Wq  = d_in[2];
    const void* Wk  = d_in[3];
    const void* Wv  = d_in[4];
    const void* Wo  = d_in[5];
    const void* Ws1 = d_in[6];
    const void* bs1 = d_in[7];
    const void* Ws2 = d_in[8];
    const void* bs2 = d_in[9];
    const void* Wf1 = d_in[10];
    const void* Wf2 = d_in[11];

    float* out1 = (float*)d_out;                       // [ROWS*EMB] f32
    float* out2 = (float*)d_out + (size_t)ROWS * EMB;  // input2 passthrough (written LAST)

    char* sb = (char*)out2;
    float* Q32   = (float*)(sb);                       // 4 MB
    float* Kt32  = (float*)(sb + (4u  << 20));         // 4 MB
    float* Vt32  = (float*)(sb + (8u  << 20));         // 4 MB
    float* heads = (float*)(sb + (12u << 20));         // 4 MB
    float* outp  = (float*)(sb + (16u << 20));         // 4 MB
    float* outp2 = (float*)(sb + (20u << 20));         // 4 MB
    float* h32   = (float*)(sb + (24u << 20));         // 4 MB
    float* Wt    = (float*)(sb + (28u << 20));                 // 192 KB
    float* Wot   = (float*)(sb + (28u << 20) + 0x30000);       // 64 KB
    float* W1t   = (float*)(sb + (28u << 20) + 0x40000);       // 256 KB
    float* W2t   = (float*)(sb + (28u << 20) + 0x80000);       // 256 KB
    float* mlp32 = (float*)(sb + (28u << 20) + 0xC0000);       // 432 B
    float* ps    = (float*)(sb + (28u << 20) + 0xC1000);       // 16 KB
    float* pq    = (float*)(sb + (28u << 20) + 0xC5000);       // 16 KB
    float* stats = (float*)(sb + (28u << 20) + 0xC9000);
    float* stats2= (float*)(sb + (28u << 20) + 0xC9100);
    int*   flags = (int*)  (sb + (28u << 20) + 0xC9200);

    const float M = (float)(SEQ * EMB);                // 131072 per batch

    hipLaunchKernelGGL(detect_kernel, dim3(9), dim3(256), 0, stream,
                       (const unsigned int*)input1, (const unsigned int*)input2,
                       (const unsigned int*)Wq, (const unsigned int*)Wk,
                       (const unsigned int*)Wv, (const unsigned int*)Wo,
                       (const unsigned int*)Ws1, (const unsigned int*)bs1,
                       (const unsigned int*)Ws2, (const unsigned int*)bs2,
                       (const unsigned int*)Wf1, (const unsigned int*)Wf2, flags);
    hipLaunchKernelGGL(convert_kernel, dim3(1793), dim3(256), 0, stream,
                       input1, Wq, Wk, Wv, Wo, Ws1, bs1, Ws2, bs2, Wf1, Wf2,
                       h32, Wt, Wot, W1t, W2t, mlp32, flags);
    hipLaunchKernelGGL(qkv_kernel, dim3(768), dim3(256), 0, stream,
                       h32, Wt, Q32, Kt32, Vt32);
    hipLaunchKernelGGL(attn_kernel, dim3(ROWS / 2), dim3(256), 0, stream,
                       Q32, Kt32, Vt32, input2, mlp32, heads, flags);
    hipLaunchKernelGGL(outproj_kernel, dim3(ROWS * EMB / 256), dim3(256), 0, stream,
                       heads, Wot, h32, outp, ps, pq);
    hipLaunchKernelGGL(stats_kernel, dim3(NB), dim3(256), 0, stream,
                       ps, pq, stats, 512, M);
    hipLaunchKernelGGL(ff_kernel, dim3(ROWS / 8), dim3(256), 0, stream,
                       outp, stats, W1t, W2t, outp2, ps, pq);
    hipLaunchKernelGGL(stats_kernel, dim3(NB), dim3(256), 0, stream,
                       ps, pq, stats2, 128, M);
    hipLaunchKernelGGL(final_kernel, dim3(ROWS * EMB / 256), dim3(256), 0, stream,
                       outp2, stats2, out1);
    hipLaunchKernelGGL(copy2_kernel, dim3(ROWS * SEQ * HN / 4 / 256), dim3(256), 0, stream,
                       input2, (uint4*)out2, flags);
}